// Round 3
// baseline (146.116 us; speedup 1.0000x reference)
//
#include <hip/hip_runtime.h>

#define NPTS  65536
#define KNB   32
#define KPn   15
#define CIN   64
#define COUT  128
#define MPTS  16            // points per block (MFMA M of GEMM2)
#define THREADS 512         // 8 waves/block; 4 blocks/CU = 32 waves/CU
#define RCAP  96            // radius-candidate cap
#define CHUNK 32            // survivors per GEMM1 K-chunk
#define ESTR  40            // infl/sfeatT row stride (elems): 80 B, 16B-aligned
#define WSTR  1032          // wl row stride (elems): 1024 + 8 pad = 2064 B
#define KSTEPS 32           // GEMM2 K steps (1024/32); k=15 rows are zero padding
#define NTILE 8             // 128 cols / 16
#define WELEMS (NTILE * KSTEPS * 64 * 8)    // 131072 bf16 elements

// pool overlay (bytes). Phase-A scratch is dead before wl is written.
#define OFF_INFL   0                        // 256*ESTR*2 = 20480
#define OFF_SFT    20480                    // 64*ESTR*2  = 5120
#define ZERO_B16   ((20480 + 5120) / 16)    // uint4 count to zero = 1600
#define OFF_RLX    25600                    // RCAP*4 = 384 each
#define OFF_RLY    (OFF_RLX + 384)
#define OFF_RLZ    (OFF_RLY + 384)
#define OFF_RLD    (OFF_RLZ + 384)
#define OFF_RSL    (OFF_RLD + 384)          // ends 27904 <= POOL_BYTES
#define POOL_BYTES (MPTS * WSTR * 2)        // 33024

typedef __attribute__((ext_vector_type(8))) short short8;
typedef __attribute__((ext_vector_type(4))) float f32x4;

__device__ __forceinline__ unsigned int f2bf(float f) {
    union { float f; unsigned int i; } v; v.f = f;
    return (v.i + 0x7fffu + ((v.i >> 16) & 1u)) >> 16;   // RNE
}
__device__ __forceinline__ unsigned int cvt_pk_bf16(float lo, float hi) {
    unsigned int r;
    asm volatile("v_cvt_pk_bf16_f32 %0, %1, %2" : "=v"(r) : "v"(lo), "v"(hi));
    return r;
}

// ---- prep: pack weights into MFMA B-fragment order + kpq/R2 ----
// GEMM2 K-enum: f in [0,1024), k = f&15 (k==15 -> zero pad), c = f>>4.
__global__ void wtrans_kernel(const float* __restrict__ w,
                              const float* __restrict__ kpts,
                              unsigned short* __restrict__ wTf,
                              float4* __restrict__ kpq_out) {  // [16]: 15 kpq + {R2}
    const int d = blockIdx.x * 256 + threadIdx.x;
    if (d < WELEMS) {
        const int j    = d & 7;
        const int lane = (d >> 3) & 63;
        const int ks   = (d >> 9) & 31;
        const int t    = d >> 14;
        const int f    = ks * 32 + ((lane >> 4) & 3) * 8 + j;
        const int k    = f & 15;
        const int c    = f >> 4;
        const int n    = t * 16 + (lane & 15);
        wTf[d] = (k < KPn)
            ? (unsigned short)f2bf(w[((size_t)k * CIN + c) * COUT + n])
            : (unsigned short)0;
    }
    if (blockIdx.x == 0 && threadIdx.x < 16) {
        const int k = threadIdx.x;
        if (k < KPn) {
            const float x = kpts[k * 3 + 0];
            const float y = kpts[k * 3 + 1];
            const float z = kpts[k * 3 + 2];
            kpq_out[k] = make_float4(x, y, z, x * x + y * y + z * z);
        } else {
            float mx = 0.f;
            for (int i = 0; i < KPn; ++i) {
                const float x = kpts[i * 3 + 0];
                const float y = kpts[i * 3 + 1];
                const float z = kpts[i * 3 + 2];
                mx = fmaxf(mx, x * x + y * y + z * z);
            }
            const float R = 0.1f + sqrtf(mx);
            kpq_out[15] = make_float4(R * R, 0.f, 0.f, 0.f);
        }
    }
}

__global__ __launch_bounds__(THREADS, 8) void kpconv_kernel(
    const float* __restrict__ pos,         // [N,3] f32
    const float* __restrict__ feats,       // [N,64] f32
    const unsigned short* __restrict__ wTf,// fragment-packed bf16 weights
    const float4* __restrict__ kpq_in,     // [16] precomputed kpq + R2
    const int*   __restrict__ neighbors,   // [N,32] int32
    float*       __restrict__ out)         // [N,128] f32
{
    __shared__ __align__(16) unsigned char pool[POOL_BYTES];
    __shared__ float  cposf[MPTS * 3];
    __shared__ float4 kpq[KPn];
    __shared__ int    nact;

    unsigned short* const wl     = (unsigned short*)pool;
    unsigned short* const infl   = (unsigned short*)(pool + OFF_INFL); // [256][ESTR]
    unsigned short* const sfeatT = (unsigned short*)(pool + OFF_SFT);  // [64][ESTR]
    float*          const rlx    = (float*)(pool + OFF_RLX);
    float*          const rly    = (float*)(pool + OFF_RLY);
    float*          const rlz    = (float*)(pool + OFF_RLZ);
    float*          const rld    = (float*)(pool + OFF_RLD);
    unsigned int*   const rsl    = (unsigned int*)(pool + OFF_RSL);    // (p<<16)|nb

    const int tid  = threadIdx.x;
    const int n0   = blockIdx.x * MPTS;
    const int lane = tid & 63;
    const int wv   = tid >> 6;             // wave id 0..7
    const int m    = lane & 15;
    const int q    = lane >> 4;

    // ---- hoisted gathers: issued BEFORE the init barrier so latency hides ----
    const int   p0  = tid >> 5;
    const int   nb0 = neighbors[(size_t)n0 * KNB + tid];
    const float qx  = pos[(size_t)nb0 * 3 + 0];
    const float qy  = pos[(size_t)nb0 * 3 + 1];
    const float qz  = pos[(size_t)nb0 * 3 + 2];
    const float R2  = kpq_in[15].x;        // uniform

    // ---- init ----
    if (tid < KPn) kpq[tid] = kpq_in[tid];
    if (tid == 0) nact = 0;
    if (tid < MPTS * 3) cposf[tid] = pos[(size_t)n0 * 3 + tid];
    __syncthreads();

    // ---- stage 1a: radius filter + compaction ----
    {
        const float rx = qx - cposf[p0 * 3 + 0];
        const float ry = qy - cposf[p0 * 3 + 1];
        const float rz = qz - cposf[p0 * 3 + 2];
        const float d2r = rx * rx + ry * ry + rz * rz;
        if (d2r < R2) {                           // ~6% survive
            const int idx = atomicAdd(&nact, 1);
            if (idx < RCAP) {
                rlx[idx] = rx; rly[idx] = ry; rlz[idx] = rz; rld[idx] = d2r;
                rsl[idx] = ((unsigned int)p0 << 16) | (unsigned int)nb0;
            }
        }
    }
    __syncthreads();

    const int E   = min(nact, RCAP);
    const int nch = (E + CHUNK - 1) >> 5;

    // ---- GEMM1: weighted[p*16+k][c] = sum_e infl[pk][e] * sfeatT[c][e] ----
    // per wave: 2 p-tiles (pa, pb) x 4 n-tiles; acc[2][4] f32x4
    f32x4 acc[2][4];
    #pragma unroll
    for (int i = 0; i < 2; ++i)
        #pragma unroll
        for (int nt = 0; nt < 4; ++nt)
            acc[i][nt] = (f32x4){0.f, 0.f, 0.f, 0.f};

    for (int ch = 0; ch < nch; ++ch) {
        // zero infl + sfeatT (contiguous region)
        {
            uint4* zp = (uint4*)pool;
            #pragma unroll
            for (int i = 0; i < 4; ++i) {
                const int idx = tid + i * THREADS;
                if (idx < ZERO_B16) zp[idx] = make_uint4(0u, 0u, 0u, 0u);
            }
        }
        __syncthreads();

        const int ce = min(E - ch * CHUNK, CHUNK);

        // staging: survivor feats -> sfeatT[c][el] bf16 (transposed, conflict-free)
        {
            const int el = tid & 31;
            const int c4 = tid >> 5;              // 0..15
            if (el < ce) {
                const int nb = (int)(rsl[ch * CHUNK + el] & 0xFFFFu);
                const float4 f = *(const float4*)(feats + (size_t)nb * CIN + c4 * 4);
                sfeatT[(c4 * 4 + 0) * ESTR + el] = (unsigned short)f2bf(f.x);
                sfeatT[(c4 * 4 + 1) * ESTR + el] = (unsigned short)f2bf(f.y);
                sfeatT[(c4 * 4 + 2) * ESTR + el] = (unsigned short)f2bf(f.z);
                sfeatT[(c4 * 4 + 3) * ESTR + el] = (unsigned short)f2bf(f.w);
            }
        }
        // kp test: direct scatter into infl (unique (e,k) slot -> no atomics)
        if (tid < ce * 16) {
            const int el = tid >> 4;
            const int k  = tid & 15;
            if (k < KPn) {
                const int e = ch * CHUNK + el;
                const float4 kp  = kpq[k];
                const float  d2r = rld[e];
                const float dot = rlx[e] * kp.x + rly[e] * kp.y + rlz[e] * kp.z;
                if (dot > 0.5f * (d2r - 0.01f + kp.w)) {
                    const float d2 = fmaxf(d2r - 2.f * dot + kp.w, 0.f);
                    const float w  = 1.0f - 10.0f * sqrtf(d2);
                    const int p = (int)(rsl[e] >> 16);
                    infl[(p * 16 + k) * ESTR + el] = (unsigned short)f2bf(w);
                }
            }
        }
        __syncthreads();

        // MFMA: a-frags for this wave's two p-tiles, b-frags per n-tile
        {
            const short8 aA = *(const short8*)(infl + ((wv * 2 + 0) * 16 + m) * ESTR + q * 8);
            const short8 aB = *(const short8*)(infl + ((wv * 2 + 1) * 16 + m) * ESTR + q * 8);
            #pragma unroll
            for (int nt = 0; nt < 4; ++nt) {
                const short8 b = *(const short8*)(sfeatT + (nt * 16 + m) * ESTR + q * 8);
                acc[0][nt] = __builtin_amdgcn_mfma_f32_16x16x32_bf16(aA, b, acc[0][nt], 0, 0, 0);
                acc[1][nt] = __builtin_amdgcn_mfma_f32_16x16x32_bf16(aB, b, acc[1][nt], 0, 0, 0);
            }
        }
        __syncthreads();   // MFMA LDS reads done (before next zero / wl write)
    }

    // ---- epilogue: weighted f32 -> bf16 pairs -> wl (f = c*16 + k layout) ----
    // D layout: col c_loc = m, rows k = q*4 + r  (tile p = wv*2+i, nt)
    #pragma unroll
    for (int i = 0; i < 2; ++i) {
        const int p = wv * 2 + i;
        #pragma unroll
        for (int nt = 0; nt < 4; ++nt) {
            const int c = nt * 16 + m;
            unsigned short* wp = wl + p * WSTR + c * 16 + q * 4;
            *(unsigned int*)(wp)     = cvt_pk_bf16(acc[i][nt][0], acc[i][nt][1]);
            *(unsigned int*)(wp + 2) = cvt_pk_bf16(acc[i][nt][2], acc[i][nt][3]);
        }
    }
    __syncthreads();

    // ---- GEMM2: out[16][128] = wl[16][1024] @ W; one N-tile per wave ----
    {
        f32x4 o = {0.f, 0.f, 0.f, 0.f};
        const unsigned short* ap = wl + m * WSTR + q * 8;
        const short8* bp = (const short8*)wTf + (size_t)wv * KSTEPS * 64 + lane;

        #pragma unroll 4
        for (int ks = 0; ks < KSTEPS; ++ks, ap += 32) {
            const short8 a = *(const short8*)ap;
            const short8 b = bp[ks * 64];
            o = __builtin_amdgcn_mfma_f32_16x16x32_bf16(a, b, o, 0, 0, 0);
        }

        const int c = wv * 16 + m;
        #pragma unroll
        for (int r = 0; r < 4; ++r)
            out[(size_t)(n0 + q * 4 + r) * COUT + c] = o[r];
    }
}

extern "C" void kernel_launch(void* const* d_in, const int* in_sizes, int n_in,
                              void* d_out, int out_size, void* d_ws, size_t ws_size,
                              hipStream_t stream) {
    const float* pos       = (const float*)d_in[0];
    const float* feats     = (const float*)d_in[1];
    const float* kpts      = (const float*)d_in[2];
    const float* weights   = (const float*)d_in[3];
    const int*   neighbors = (const int*)d_in[4];
    float*       out       = (float*)d_out;
    unsigned short* wTf    = (unsigned short*)d_ws;               // 262144 B
    float4* kpq            = (float4*)((char*)d_ws + WELEMS * 2); // 256 B

    wtrans_kernel<<<WELEMS / 256, 256, 0, stream>>>(weights, kpts, wTf, kpq);
    kpconv_kernel<<<NPTS / MPTS, THREADS, 0, stream>>>(
        pos, feats, wTf, kpq, neighbors, out);
}

// Round 4
// 136.049 us; speedup vs baseline: 1.0740x; 1.0740x over previous
//
#include <hip/hip_runtime.h>

#define NPTS  65536
#define KNB   32
#define KPn   15
#define CIN   64
#define COUT  128
#define MPTS  16            // points per block (MFMA M of GEMM2)
#define THREADS 512         // 8 waves/block; 4 blocks/CU = 32 waves/CU
#define RCAP  96            // radius-candidate cap
#define CHUNK 32            // survivors per GEMM1 K-chunk
#define ESTR  40            // infl/sfeatT row stride (elems): 80 B, 16B-aligned
#define WSTR  1032          // wl row stride (elems): 1024 + 8 pad = 2064 B
#define KSTEPS 32           // GEMM2 K steps (1024/32); k=15 rows are zero padding
#define NTILE 8             // 128 cols / 16
#define WELEMS (NTILE * KSTEPS * 64 * 8)    // 131072 bf16 elements

// pool map (bytes):
//   [0      .. 16512)  wl rows 0-7   (written at end of pass 0)
//   [16512  .. 33024)  wl rows 8-15  (written at end of pass 1)
//   scratch (infl+sfeatT, 15360 B) lives at 16512 during BOTH passes:
//     pass 0: disjoint from wl rows 0-7 -> safe
//     pass 1: overlays wl rows 8-15, which are written only AFTER the last
//             MFMA read of scratch (barrier-ordered) -> safe
#define POOL_BYTES (MPTS * WSTR * 2)        // 33024
#define OFF_SCR    16512
#define OFF_SFT    (OFF_SCR + 128 * ESTR * 2)   // 16512 + 10240 = 26752
#define ZINFL_B16  (128 * ESTR * 2 / 16)        // 640 uint4 to zero per chunk

typedef __attribute__((ext_vector_type(8))) short short8;
typedef __attribute__((ext_vector_type(4))) float f32x4;

__device__ __forceinline__ unsigned int f2bf(float f) {
    union { float f; unsigned int i; } v; v.f = f;
    return (v.i + 0x7fffu + ((v.i >> 16) & 1u)) >> 16;   // RNE
}
__device__ __forceinline__ unsigned int cvt_pk_bf16(float lo, float hi) {
    unsigned int r;
    asm volatile("v_cvt_pk_bf16_f32 %0, %1, %2" : "=v"(r) : "v"(lo), "v"(hi));
    return r;
}

// ---- prep: pack weights into MFMA B-fragment order + kpq/R2 ----
// GEMM2 K-enum: f in [0,1024), k = f&15 (k==15 -> zero pad), c = f>>4.
__global__ void wtrans_kernel(const float* __restrict__ w,
                              const float* __restrict__ kpts,
                              unsigned short* __restrict__ wTf,
                              float4* __restrict__ kpq_out) {  // [16]: 15 kpq + {R2}
    const int d = blockIdx.x * 256 + threadIdx.x;
    if (d < WELEMS) {
        const int j    = d & 7;
        const int lane = (d >> 3) & 63;
        const int ks   = (d >> 9) & 31;
        const int t    = d >> 14;
        const int f    = ks * 32 + ((lane >> 4) & 3) * 8 + j;
        const int k    = f & 15;
        const int c    = f >> 4;
        const int n    = t * 16 + (lane & 15);
        wTf[d] = (k < KPn)
            ? (unsigned short)f2bf(w[((size_t)k * CIN + c) * COUT + n])
            : (unsigned short)0;
    }
    if (blockIdx.x == 0 && threadIdx.x < 16) {
        const int k = threadIdx.x;
        if (k < KPn) {
            const float x = kpts[k * 3 + 0];
            const float y = kpts[k * 3 + 1];
            const float z = kpts[k * 3 + 2];
            kpq_out[k] = make_float4(x, y, z, x * x + y * y + z * z);
        } else {
            float mx = 0.f;
            for (int i = 0; i < KPn; ++i) {
                const float x = kpts[i * 3 + 0];
                const float y = kpts[i * 3 + 1];
                const float z = kpts[i * 3 + 2];
                mx = fmaxf(mx, x * x + y * y + z * z);
            }
            const float R = 0.1f + sqrtf(mx);
            kpq_out[15] = make_float4(R * R, 0.f, 0.f, 0.f);
        }
    }
}

__global__ __launch_bounds__(THREADS, 8) void kpconv_kernel(
    const float* __restrict__ pos,         // [N,3] f32
    const float* __restrict__ feats,       // [N,64] f32
    const unsigned short* __restrict__ wTf,// fragment-packed bf16 weights
    const float4* __restrict__ kpq_in,     // [16] precomputed kpq + R2
    const int*   __restrict__ neighbors,   // [N,32] int32
    float*       __restrict__ out)         // [N,128] f32
{
    __shared__ __align__(16) unsigned char pool[POOL_BYTES];
    __shared__ float  cposf[MPTS * 3];
    __shared__ float4 kpq[KPn];
    __shared__ float  rlx[RCAP], rly[RCAP], rlz[RCAP], rld[RCAP];
    __shared__ unsigned int rsl[RCAP];     // (p<<16) | nb
    __shared__ int    nact;

    unsigned short* const wl   = (unsigned short*)pool;
    unsigned short* const infl = (unsigned short*)(pool + OFF_SCR); // [128][ESTR]
    unsigned short* const sfT  = (unsigned short*)(pool + OFF_SFT); // [64][ESTR]

    const int tid  = threadIdx.x;
    const int n0   = blockIdx.x * MPTS;
    const int lane = tid & 63;
    const int wv   = tid >> 6;             // wave id 0..7 = p_local (per pass)
    const int m    = lane & 15;
    const int q    = lane >> 4;

    // ---- hoisted gathers: issued BEFORE the init barrier so latency hides ----
    const int   p0  = tid >> 5;
    const int   nb0 = neighbors[(size_t)n0 * KNB + tid];
    const float qx  = pos[(size_t)nb0 * 3 + 0];
    const float qy  = pos[(size_t)nb0 * 3 + 1];
    const float qz  = pos[(size_t)nb0 * 3 + 2];
    const float R2  = kpq_in[15].x;        // uniform

    // ---- init ----
    if (tid < KPn) kpq[tid] = kpq_in[tid];
    if (tid == 0) nact = 0;
    if (tid < MPTS * 3) cposf[tid] = pos[(size_t)n0 * 3 + tid];
    __syncthreads();

    // ---- stage 1a: radius filter + compaction ----
    {
        const float rx = qx - cposf[p0 * 3 + 0];
        const float ry = qy - cposf[p0 * 3 + 1];
        const float rz = qz - cposf[p0 * 3 + 2];
        const float d2r = rx * rx + ry * ry + rz * rz;
        if (d2r < R2) {                           // ~6% survive
            const int idx = atomicAdd(&nact, 1);
            if (idx < RCAP) {
                rlx[idx] = rx; rly[idx] = ry; rlz[idx] = rz; rld[idx] = d2r;
                rsl[idx] = ((unsigned int)p0 << 16) | (unsigned int)nb0;
            }
        }
    }
    __syncthreads();

    const int E   = min(nact, RCAP);
    const int nch = (E + CHUNK - 1) >> 5;

    // ---- GEMM1, two passes over p-halves: acc = 4 f32x4 = 16 VGPR/thread ----
    // weighted[(pass*8+wv)*16+k][c] = sum_e infl[wv*16+k][e] * sfT[c][e]
    for (int pass = 0; pass < 2; ++pass) {
        f32x4 acc[4];
        #pragma unroll
        for (int nt = 0; nt < 4; ++nt) acc[nt] = (f32x4){0.f, 0.f, 0.f, 0.f};

        for (int ch = 0; ch < nch; ++ch) {
            const int ce = min(E - ch * CHUNK, CHUNK);

            // zero infl (sparse-scattered) + stage sfT (fully written, 0-padded)
            {
                uint4* zp = (uint4*)infl;
                #pragma unroll
                for (int i = 0; i < 2; ++i) {
                    const int idx = tid + i * THREADS;
                    if (idx < ZINFL_B16) zp[idx] = make_uint4(0u, 0u, 0u, 0u);
                }
                const int el = tid & 31;
                const int c4 = tid >> 5;              // 0..15
                float4 f = make_float4(0.f, 0.f, 0.f, 0.f);
                if (el < ce) {
                    const int nb = (int)(rsl[ch * CHUNK + el] & 0xFFFFu);
                    f = *(const float4*)(feats + (size_t)nb * CIN + c4 * 4);
                }
                sfT[(c4 * 4 + 0) * ESTR + el] = (unsigned short)f2bf(f.x);
                sfT[(c4 * 4 + 1) * ESTR + el] = (unsigned short)f2bf(f.y);
                sfT[(c4 * 4 + 2) * ESTR + el] = (unsigned short)f2bf(f.z);
                sfT[(c4 * 4 + 3) * ESTR + el] = (unsigned short)f2bf(f.w);
            }
            __syncthreads();

            // kp test: direct scatter into infl for this p-half only
            if (tid < ce * 16) {
                const int el = tid >> 4;
                const int k  = tid & 15;
                if (k < KPn) {
                    const int e = ch * CHUNK + el;
                    const int p = (int)(rsl[e] >> 16);
                    if ((p >> 3) == pass) {
                        const float4 kp  = kpq[k];
                        const float  d2r = rld[e];
                        const float dot = rlx[e]*kp.x + rly[e]*kp.y + rlz[e]*kp.z;
                        if (dot > 0.5f * (d2r - 0.01f + kp.w)) {
                            const float d2 = fmaxf(d2r - 2.f * dot + kp.w, 0.f);
                            const float w  = 1.0f - 10.0f * sqrtf(d2);
                            infl[((p & 7) * 16 + k) * ESTR + el] =
                                (unsigned short)f2bf(w);
                        }
                    }
                }
            }
            __syncthreads();

            // MFMA: wave wv owns p_local = wv; 4 n-tiles
            {
                const short8 a = *(const short8*)(infl + (wv * 16 + m) * ESTR + q * 8);
                #pragma unroll
                for (int nt = 0; nt < 4; ++nt) {
                    const short8 b = *(const short8*)(sfT + (nt * 16 + m) * ESTR + q * 8);
                    acc[nt] = __builtin_amdgcn_mfma_f32_16x16x32_bf16(a, b, acc[nt], 0, 0, 0);
                }
            }
            __syncthreads();   // scratch reads done (next zero / wl-row write)
        }

        // epilogue: weighted f32 -> bf16 -> wl row (pass*8 + wv)
        // D layout: col c_loc = m, rows k = q*4 + r;  wl f-enum: f = c*16 + k
        {
            const int prow = pass * 8 + wv;
            #pragma unroll
            for (int nt = 0; nt < 4; ++nt) {
                const int c = nt * 16 + m;
                unsigned short* wp = wl + prow * WSTR + c * 16 + q * 4;
                *(unsigned int*)(wp)     = cvt_pk_bf16(acc[nt][0], acc[nt][1]);
                *(unsigned int*)(wp + 2) = cvt_pk_bf16(acc[nt][2], acc[nt][3]);
            }
        }
    }
    __syncthreads();

    // ---- GEMM2: out[16][128] = wl[16][1024] @ W; one N-tile per wave ----
    {
        f32x4 o = {0.f, 0.f, 0.f, 0.f};
        const unsigned short* ap = wl + m * WSTR + q * 8;
        const short8* bp = (const short8*)wTf + (size_t)wv * KSTEPS * 64 + lane;

        #pragma unroll 4
        for (int ks = 0; ks < KSTEPS; ++ks, ap += 32) {
            const short8 a = *(const short8*)ap;
            const short8 b = bp[ks * 64];
            o = __builtin_amdgcn_mfma_f32_16x16x32_bf16(a, b, o, 0, 0, 0);
        }

        const int c = wv * 16 + m;
        #pragma unroll
        for (int r = 0; r < 4; ++r)
            out[(size_t)(n0 + q * 4 + r) * COUT + c] = o[r];
    }
}

extern "C" void kernel_launch(void* const* d_in, const int* in_sizes, int n_in,
                              void* d_out, int out_size, void* d_ws, size_t ws_size,
                              hipStream_t stream) {
    const float* pos       = (const float*)d_in[0];
    const float* feats     = (const float*)d_in[1];
    const float* kpts      = (const float*)d_in[2];
    const float* weights   = (const float*)d_in[3];
    const int*   neighbors = (const int*)d_in[4];
    float*       out       = (float*)d_out;
    unsigned short* wTf    = (unsigned short*)d_ws;               // 262144 B
    float4* kpq            = (float4*)((char*)d_ws + WELEMS * 2); // 256 B

    wtrans_kernel<<<WELEMS / 256, 256, 0, stream>>>(weights, kpts, wTf, kpq);
    kpconv_kernel<<<NPTS / MPTS, THREADS, 0, stream>>>(
        pos, feats, wTf, kpq, neighbors, out);
}